// Round 1
// baseline (6523.159 us; speedup 1.0000x reference)
//
#include <hip/hip_runtime.h>
#include <hip/hip_bf16.h>
#include <math.h>

#define TOK    4096   // B*S
#define HS     2048
#define CONVD  8192
#define KEYD   2048
#define VALD   4096
#define NKH    16
#define NVH    32
#define DKH    128
#define DVH    128
#define SEQ    2048
#define NBATCH 2
#define EPSF   1e-6f

// ---------------- GEMM: C[M,N] = A[M,K] * B[N,K]^T  (fp32) ----------------
// 64x64 tile, 256 threads, 4x4 per thread, BK=16, float4 global loads.
__global__ __launch_bounds__(256) void gemm_nt(
    const float* __restrict__ A, const float* __restrict__ B,
    float* __restrict__ C, int M, int N, int K) {
  __shared__ float As[16][68];  // +4 pad keeps 16B alignment per row
  __shared__ float Bs[16][68];
  const int tx = threadIdx.x & 15;
  const int ty = threadIdx.x >> 4;
  const int row0 = blockIdx.y * 64;
  const int col0 = blockIdx.x * 64;
  const int lr = threadIdx.x >> 2;        // 0..63 row within tile
  const int lc = (threadIdx.x & 3) * 4;   // 0,4,8,12 col within BK
  float acc[4][4] = {};
  for (int k0 = 0; k0 < K; k0 += 16) {
    float4 av = *(const float4*)&A[(size_t)(row0 + lr) * K + (k0 + lc)];
    float4 bv = *(const float4*)&B[(size_t)(col0 + lr) * K + (k0 + lc)];
    As[lc + 0][lr] = av.x; As[lc + 1][lr] = av.y;
    As[lc + 2][lr] = av.z; As[lc + 3][lr] = av.w;
    Bs[lc + 0][lr] = bv.x; Bs[lc + 1][lr] = bv.y;
    Bs[lc + 2][lr] = bv.z; Bs[lc + 3][lr] = bv.w;
    __syncthreads();
    #pragma unroll
    for (int kk = 0; kk < 16; kk++) {
      float a[4], b[4];
      #pragma unroll
      for (int i = 0; i < 4; i++) a[i] = As[kk][ty * 4 + i];
      #pragma unroll
      for (int i = 0; i < 4; i++) b[i] = Bs[kk][tx * 4 + i];
      #pragma unroll
      for (int i = 0; i < 4; i++)
        #pragma unroll
        for (int j = 0; j < 4; j++)
          acc[i][j] += a[i] * b[j];
    }
    __syncthreads();
  }
  #pragma unroll
  for (int i = 0; i < 4; i++) {
    float4 v = make_float4(acc[i][0], acc[i][1], acc[i][2], acc[i][3]);
    *(float4*)&C[(size_t)(row0 + ty * 4 + i) * N + (col0 + tx * 4)] = v;
  }
}

// ------------- causal depthwise conv (K=4) + SiLU -------------
// in:  qkv [TOK, CONVD]   out: mix [TOK, CONVD]
__global__ __launch_bounds__(256) void conv_silu(
    const float* __restrict__ qkv, const float* __restrict__ cw,
    float* __restrict__ mix) {
  size_t idx = (size_t)blockIdx.x * 256 + threadIdx.x;  // over TOK*CONVD
  int c = (int)(idx % CONVD);
  size_t t = idx / CONVD;
  int s = (int)(t % SEQ);
  float w0 = cw[c * 4 + 0], w1 = cw[c * 4 + 1], w2 = cw[c * 4 + 2], w3 = cw[c * 4 + 3];
  const float* col = qkv + t * CONVD + c;
  float acc = w3 * col[0];
  if (s >= 1) acc += w2 * col[-(ptrdiff_t)CONVD];
  if (s >= 2) acc += w1 * col[-2 * (ptrdiff_t)CONVD];
  if (s >= 3) acc += w0 * col[-3 * (ptrdiff_t)CONVD];
  float sig = 1.f / (1.f + expf(-acc));
  mix[t * CONVD + c] = acc * sig;
}

// ------------- gates: ge = exp(-exp(A_log)*softplus(a+dt_bias)), beta=sigmoid(b)
// ba: [TOK, 64] (b:0..31, a:32..63) -> gate: [TOK, 64] (ge:0..31, beta:32..63)
__global__ __launch_bounds__(256) void gates_kernel(
    const float* __restrict__ ba, const float* __restrict__ A_log,
    const float* __restrict__ dt_bias, float* __restrict__ gate) {
  int idx = blockIdx.x * 256 + threadIdx.x;  // TOK*NVH
  int h = idx & 31;
  size_t t = (size_t)(idx >> 5);
  float bv = ba[t * 64 + h];
  float av = ba[t * 64 + 32 + h];
  float beta = 1.f / (1.f + expf(-bv));
  float xx = av + dt_bias[h];
  float sp = (xx > 20.f) ? xx : log1pf(expf(xx));
  float ge = expf(-expf(A_log[h]) * sp);
  gate[t * 64 + h] = ge;
  gate[t * 64 + 32 + h] = beta;
}

// ------------- per-head L2 norm of q and k (in place in mix) -------------
// one wave per (token, head-slot): slot 0..15 = q heads, 16..31 = k heads
__global__ __launch_bounds__(256) void l2norm_qk(float* __restrict__ mix) {
  int wid = (blockIdx.x * 256 + threadIdx.x) >> 6;  // TOK*32 waves
  int lane = threadIdx.x & 63;
  size_t t = (size_t)(wid >> 5);
  int hh = wid & 31;
  float* p = mix + t * CONVD + (size_t)hh * DKH;  // q: cols 0..2047, k: 2048..4095
  float v0 = p[lane], v1 = p[lane + 64];
  float ss = v0 * v0 + v1 * v1;
  #pragma unroll
  for (int off = 32; off >= 1; off >>= 1) ss += __shfl_xor(ss, off, 64);
  float sc = rsqrtf(ss + EPSF);
  p[lane] = v0 * sc;
  p[lane + 64] = v1 * sc;
}

// ------------- sequential delta-rule scan -------------
// grid: NBATCH*NVH*4 blocks (v split 4x32); 256 threads: v = tid&31, kseg = tid>>5 (8 segs x 16 k)
__global__ __launch_bounds__(256) void scan_kernel(
    const float* __restrict__ mix, const float* __restrict__ gate,
    float* __restrict__ core) {
  int blk = blockIdx.x;
  int vc = blk & 3;
  int h = (blk >> 2) & 31;
  int b = blk >> 7;
  int tid = threadIdx.x;
  int v = tid & 31;
  int kseg = tid >> 5;

  __shared__ float k_sh[128];
  __shared__ float q_sh[128];
  __shared__ float v_sh[32];
  __shared__ float part[256];
  __shared__ float part2[256];

  float st[16];
  #pragma unroll
  for (int i = 0; i < 16; i++) st[i] = 0.f;

  const int kh = h >> 1;  // head repetition: value head h uses key head h/2
  const float* qbase = mix + (size_t)b * SEQ * CONVD + (size_t)kh * DKH;
  const float* kbase = qbase + KEYD;
  const float* vbase = mix + (size_t)b * SEQ * CONVD + 2 * KEYD + (size_t)h * DVH + vc * 32;
  const float* gbase = gate + (size_t)b * SEQ * 64;
  float* obase = core + (size_t)b * SEQ * VALD + (size_t)h * DVH + vc * 32 + v;

  for (int s = 0; s < SEQ; s++) {
    size_t row = (size_t)s * CONVD;
    if (tid < 128) k_sh[tid] = kbase[row + tid];
    else           q_sh[tid - 128] = qbase[row + (tid - 128)];
    if (tid < 32)  v_sh[tid] = vbase[row + tid];
    float ge = gbase[s * 64 + h];
    float beta = gbase[s * 64 + 32 + h];
    __syncthreads();

    float kr[16], qr[16];
    #pragma unroll
    for (int j = 0; j < 16; j++) { kr[j] = k_sh[kseg * 16 + j]; qr[j] = q_sh[kseg * 16 + j]; }

    float p0 = 0.f, p1 = 0.f;
    #pragma unroll
    for (int j = 0; j < 16; j += 2) { p0 += kr[j] * st[j]; p1 += kr[j + 1] * st[j + 1]; }
    part[tid] = p0 + p1;
    __syncthreads();

    float kv = 0.f;
    #pragma unroll
    for (int ss2 = 0; ss2 < 8; ss2++) kv += part[ss2 * 32 + v];
    float delta = beta * (v_sh[v] - ge * kv);

    float op0 = 0.f, op1 = 0.f;
    #pragma unroll
    for (int j = 0; j < 16; j += 2) {
      st[j] = ge * st[j] + kr[j] * delta;
      op0 += qr[j] * st[j];
      st[j + 1] = ge * st[j + 1] + kr[j + 1] * delta;
      op1 += qr[j + 1] * st[j + 1];
    }
    part2[tid] = op0 + op1;
    __syncthreads();

    if (tid < 32) {
      float o = 0.f;
      #pragma unroll
      for (int ss2 = 0; ss2 < 8; ss2++) o += part2[ss2 * 32 + v];
      obase[row == 0 ? 0 : (size_t)s * VALD] = o;  // row var reused; index is s*VALD
    }
  }
}

// ------------- RMSNorm(1+w) * silu(z), in place on core -------------
__global__ __launch_bounds__(256) void rmsnorm_silu(
    float* __restrict__ core, const float* __restrict__ zbuf,
    const float* __restrict__ norm_w) {
  int t = blockIdx.x;
  int tid = threadIdx.x;
  float* row = core + (size_t)t * VALD;
  const float* zrow = zbuf + (size_t)t * VALD;
  float vals[16];
  float ss = 0.f;
  #pragma unroll
  for (int i = 0; i < 16; i++) { float x = row[tid + i * 256]; vals[i] = x; ss += x * x; }
  #pragma unroll
  for (int off = 32; off >= 1; off >>= 1) ss += __shfl_xor(ss, off, 64);
  __shared__ float red[4];
  if ((tid & 63) == 0) red[tid >> 6] = ss;
  __syncthreads();
  float tot = red[0] + red[1] + red[2] + red[3];
  float scale = rsqrtf(tot * (1.f / VALD) + EPSF);
  #pragma unroll
  for (int i = 0; i < 16; i++) {
    int c = tid + i * 256;
    float z = zrow[c];
    float sz = z / (1.f + expf(-z));
    row[c] = vals[i] * scale * (1.f + norm_w[c]) * sz;
  }
}

extern "C" void kernel_launch(void* const* d_in, const int* in_sizes, int n_in,
                              void* d_out, int out_size, void* d_ws, size_t ws_size,
                              hipStream_t stream) {
  const float* x       = (const float*)d_in[0];
  const float* W_qkvz  = (const float*)d_in[1];
  const float* W_ba    = (const float*)d_in[2];
  const float* conv_w  = (const float*)d_in[3];
  const float* dt_bias = (const float*)d_in[4];
  const float* A_log   = (const float*)d_in[5];
  const float* norm_w  = (const float*)d_in[6];
  const float* W_out   = (const float*)d_in[7];
  float* out = (float*)d_out;

  float* ws = (float*)d_ws;
  float* buf_qkv  = ws;                                   // 4096*8192 (later reused for z)
  float* buf_mix  = buf_qkv + (size_t)TOK * CONVD;        // 4096*8192
  float* buf_ba   = buf_mix + (size_t)TOK * CONVD;        // 4096*64
  float* buf_gate = buf_ba + (size_t)TOK * 64;            // 4096*64
  float* buf_core = buf_gate + (size_t)TOK * 64;          // 4096*4096
  float* buf_z    = buf_qkv;                              // reuse qkv region after conv

  // 1) qkv projection: [TOK, 8192] = x @ W_qkvz[0:8192]^T
  gemm_nt<<<dim3(CONVD / 64, TOK / 64), 256, 0, stream>>>(x, W_qkvz, buf_qkv, TOK, CONVD, HS);
  // 2) ba projection: [TOK, 64]
  gemm_nt<<<dim3(1, TOK / 64), 256, 0, stream>>>(x, W_ba, buf_ba, TOK, 64, HS);
  // 3) conv + silu (consumes buf_qkv)
  conv_silu<<<(int)(((size_t)TOK * CONVD) / 256), 256, 0, stream>>>(buf_qkv, conv_w, buf_mix);
  // 4) z projection into the (now free) qkv region: [TOK, 4096]
  gemm_nt<<<dim3(VALD / 64, TOK / 64), 256, 0, stream>>>(
      x, W_qkvz + (size_t)(2 * KEYD + VALD) * HS, buf_z, TOK, VALD, HS);
  // 5) gates
  gates_kernel<<<TOK * NVH / 256, 256, 0, stream>>>(buf_ba, A_log, dt_bias, buf_gate);
  // 6) l2 norm q,k
  l2norm_qk<<<TOK * 32 / 4, 256, 0, stream>>>(buf_mix);
  // 7) scan
  scan_kernel<<<NBATCH * NVH * 4, 256, 0, stream>>>(buf_mix, buf_gate, buf_core);
  // 8) rmsnorm * silu(z)
  rmsnorm_silu<<<TOK, 256, 0, stream>>>(buf_core, buf_z, norm_w);
  // 9) output projection: [TOK, 2048] = core @ W_out^T
  gemm_nt<<<dim3(HS / 64, TOK / 64), 256, 0, stream>>>(buf_core, W_out, out, TOK, HS, VALD);
}

// Round 2
// 2378.333 us; speedup vs baseline: 2.7427x; 2.7427x over previous
//
#include <hip/hip_runtime.h>
#include <hip/hip_bf16.h>
#include <math.h>

#define TOK    4096   // B*S
#define HS     2048
#define CONVD  8192
#define KEYD   2048
#define VALD   4096
#define NKH    16
#define NVH    32
#define DKH    128
#define DVH    128
#define SEQ    2048
#define NBATCH 2
#define EPSF   1e-6f

typedef __attribute__((ext_vector_type(8))) short short8;
typedef __attribute__((ext_vector_type(4))) float floatx4;

static __device__ __forceinline__ unsigned short f2bf(float x) {
  union { float f; unsigned u; } c; c.f = x;
  unsigned r = (c.u + 0x7FFF + ((c.u >> 16) & 1)) >> 16;
  return (unsigned short)r;
}

// ---------------- fp32 GEMM (kept for the tiny ba projection) ----------------
__global__ __launch_bounds__(256) void gemm_nt(
    const float* __restrict__ A, const float* __restrict__ B,
    float* __restrict__ C, int M, int N, int K) {
  __shared__ float As[16][68];
  __shared__ float Bs[16][68];
  const int tx = threadIdx.x & 15;
  const int ty = threadIdx.x >> 4;
  const int row0 = blockIdx.y * 64;
  const int col0 = blockIdx.x * 64;
  const int lr = threadIdx.x >> 2;
  const int lc = (threadIdx.x & 3) * 4;
  float acc[4][4] = {};
  for (int k0 = 0; k0 < K; k0 += 16) {
    float4 av = *(const float4*)&A[(size_t)(row0 + lr) * K + (k0 + lc)];
    float4 bv = *(const float4*)&B[(size_t)(col0 + lr) * K + (k0 + lc)];
    As[lc + 0][lr] = av.x; As[lc + 1][lr] = av.y;
    As[lc + 2][lr] = av.z; As[lc + 3][lr] = av.w;
    Bs[lc + 0][lr] = bv.x; Bs[lc + 1][lr] = bv.y;
    Bs[lc + 2][lr] = bv.z; Bs[lc + 3][lr] = bv.w;
    __syncthreads();
    #pragma unroll
    for (int kk = 0; kk < 16; kk++) {
      float a[4], b[4];
      #pragma unroll
      for (int i = 0; i < 4; i++) a[i] = As[kk][ty * 4 + i];
      #pragma unroll
      for (int i = 0; i < 4; i++) b[i] = Bs[kk][tx * 4 + i];
      #pragma unroll
      for (int i = 0; i < 4; i++)
        #pragma unroll
        for (int j = 0; j < 4; j++)
          acc[i][j] += a[i] * b[j];
    }
    __syncthreads();
  }
  #pragma unroll
  for (int i = 0; i < 4; i++) {
    float4 v = make_float4(acc[i][0], acc[i][1], acc[i][2], acc[i][3]);
    *(float4*)&C[(size_t)(row0 + ty * 4 + i) * N + (col0 + tx * 4)] = v;
  }
}

// ---------------- fp32 -> bf16 cast ----------------
__global__ __launch_bounds__(256) void cast_bf16(
    const float4* __restrict__ src, ushort4* __restrict__ dst, int n4) {
  int i = blockIdx.x * 256 + threadIdx.x;
  if (i < n4) {
    float4 v = src[i];
    ushort4 o;
    o.x = f2bf(v.x); o.y = f2bf(v.y); o.z = f2bf(v.z); o.w = f2bf(v.w);
    dst[i] = o;
  }
}

// ---------------- bf16 MFMA GEMM: C[M,N] = A[M,K] * B[N,K]^T ----------------
// 128x128 tile, 256 threads (4 waves, 2x2 of 64x64), BK=32, global_load_lds x16.
__global__ __launch_bounds__(256) void gemm_bf16_nt(
    const ushort* __restrict__ A, const ushort* __restrict__ B,
    float* __restrict__ C, int M, int N, int K) {
  __shared__ ushort Asm[128 * 32];
  __shared__ ushort Bsm[128 * 32];
  const int tid = threadIdx.x;
  const int w = tid >> 6, l = tid & 63;
  const int row0 = blockIdx.y * 128, col0 = blockIdx.x * 128;
  const int wm = w >> 1, wn = w & 1;

  floatx4 acc[4][4];
  #pragma unroll
  for (int i = 0; i < 4; i++)
    #pragma unroll
    for (int j = 0; j < 4; j++)
      acc[i][j] = (floatx4){0.f, 0.f, 0.f, 0.f};

  const int srow = w * 16 + (l >> 2);   // + c*64 per staging call
  const int scol = (l & 3) * 8;
  const ushort* Ag = A + (size_t)(row0 + srow) * K + scol;
  const ushort* Bg = B + (size_t)(col0 + srow) * K + scol;

  for (int k0 = 0; k0 < K; k0 += 32) {
    #pragma unroll
    for (int c = 0; c < 2; c++) {
      __builtin_amdgcn_global_load_lds(
          (const __attribute__((address_space(1))) void*)(Ag + (size_t)(c * 64) * K + k0),
          (__attribute__((address_space(3))) void*)&Asm[(c * 64 + w * 16) * 32],
          16, 0, 0);
      __builtin_amdgcn_global_load_lds(
          (const __attribute__((address_space(1))) void*)(Bg + (size_t)(c * 64) * K + k0),
          (__attribute__((address_space(3))) void*)&Bsm[(c * 64 + w * 16) * 32],
          16, 0, 0);
    }
    __syncthreads();
    short8 af[4], bfv[4];
    #pragma unroll
    for (int i = 0; i < 4; i++) {
      af[i]  = *(const short8*)&Asm[(wm * 64 + i * 16 + (l & 15)) * 32 + (l >> 4) * 8];
      bfv[i] = *(const short8*)&Bsm[(wn * 64 + i * 16 + (l & 15)) * 32 + (l >> 4) * 8];
    }
    #pragma unroll
    for (int i = 0; i < 4; i++)
      #pragma unroll
      for (int j = 0; j < 4; j++)
        acc[i][j] = __builtin_amdgcn_mfma_f32_16x16x32_bf16(af[i], bfv[j], acc[i][j], 0, 0, 0);
    __syncthreads();
  }

  const int cl = l & 15, rq = l >> 4;
  #pragma unroll
  for (int i = 0; i < 4; i++) {
    int r0 = row0 + wm * 64 + i * 16 + rq * 4;
    #pragma unroll
    for (int j = 0; j < 4; j++) {
      int cc = col0 + wn * 64 + j * 16 + cl;
      #pragma unroll
      for (int r = 0; r < 4; r++)
        C[(size_t)(r0 + r) * N + cc] = acc[i][j][r];
    }
  }
}

// ------------- causal depthwise conv (K=4) + SiLU -------------
__global__ __launch_bounds__(256) void conv_silu(
    const float* __restrict__ qkv, const float* __restrict__ cw,
    float* __restrict__ mix) {
  size_t idx = (size_t)blockIdx.x * 256 + threadIdx.x;
  int c = (int)(idx % CONVD);
  size_t t = idx / CONVD;
  int s = (int)(t % SEQ);
  float w0 = cw[c * 4 + 0], w1 = cw[c * 4 + 1], w2 = cw[c * 4 + 2], w3 = cw[c * 4 + 3];
  const float* col = qkv + t * CONVD + c;
  float acc = w3 * col[0];
  if (s >= 1) acc += w2 * col[-(ptrdiff_t)CONVD];
  if (s >= 2) acc += w1 * col[-2 * (ptrdiff_t)CONVD];
  if (s >= 3) acc += w0 * col[-3 * (ptrdiff_t)CONVD];
  float sig = 1.f / (1.f + expf(-acc));
  mix[t * CONVD + c] = acc * sig;
}

// ------------- gates (in place on ba buffer) -------------
// ba layout [TOK,64]: b at [h], a at [32+h]  ->  ge at [h], beta at [32+h]
__global__ __launch_bounds__(256) void gates_kernel(
    float* __restrict__ ba, const float* __restrict__ A_log,
    const float* __restrict__ dt_bias) {
  int idx = blockIdx.x * 256 + threadIdx.x;
  int h = idx & 31;
  size_t t = (size_t)(idx >> 5);
  float bv = ba[t * 64 + h];
  float av = ba[t * 64 + 32 + h];
  float beta = 1.f / (1.f + expf(-bv));
  float xx = av + dt_bias[h];
  float sp = (xx > 20.f) ? xx : log1pf(expf(xx));
  float ge = expf(-expf(A_log[h]) * sp);
  ba[t * 64 + h] = ge;
  ba[t * 64 + 32 + h] = beta;
}

// ------------- per-head L2 norm of q and k (in place in mix) -------------
__global__ __launch_bounds__(256) void l2norm_qk(float* __restrict__ mix) {
  int wid = (blockIdx.x * 256 + threadIdx.x) >> 6;
  int lane = threadIdx.x & 63;
  size_t t = (size_t)(wid >> 5);
  int hh = wid & 31;
  float* p = mix + t * CONVD + (size_t)hh * DKH;
  float v0 = p[lane], v1 = p[lane + 64];
  float ss = v0 * v0 + v1 * v1;
  #pragma unroll
  for (int off = 32; off >= 1; off >>= 1) ss += __shfl_xor(ss, off, 64);
  float sc = rsqrtf(ss + EPSF);
  p[lane] = v0 * sc;
  p[lane + 64] = v1 * sc;
}

// ------------- sequential delta-rule scan: single-wave blocks -------------
// grid: 1024 = b(2) x h(32) x vc(16); 64 threads; lane = kseg(8)*8 + vsub(8)
// state per lane: 16 k x 1 v. All reductions intra-wave (shfl_xor 8/16/32).
__global__ __launch_bounds__(64) void scan_kernel(
    const float* __restrict__ mix, const float* __restrict__ gate,
    float* __restrict__ core) {
  const int blk = blockIdx.x;
  const int vc = blk & 15;
  const int h = (blk >> 4) & 31;
  const int b = blk >> 9;
  const int lane = threadIdx.x;
  const int kseg = lane >> 3;
  const int vs = lane & 7;

  __shared__ float kbuf[2][128];
  __shared__ float qbuf[2][128];
  __shared__ float vbuf[2][8];

  const int kh = h >> 1;
  const float* qrow = mix + (size_t)b * SEQ * CONVD + (size_t)kh * DKH;
  const float* krow = qrow + KEYD;
  const float* vrow = mix + (size_t)b * SEQ * CONVD + 2 * KEYD + (size_t)h * DVH + vc * 8;
  const float* grow = gate + (size_t)b * SEQ * 64;
  float* orow = core + (size_t)b * SEQ * VALD + (size_t)h * DVH + vc * 8;

  float st[16];
  #pragma unroll
  for (int i = 0; i < 16; i++) st[i] = 0.f;

  // step 0 -> LDS buf[0]
  {
    float2 k0 = *(const float2*)(krow + 2 * lane);
    float2 q0 = *(const float2*)(qrow + 2 * lane);
    ((float2*)kbuf[0])[lane] = k0;
    ((float2*)qbuf[0])[lane] = q0;
    if (lane < 8) vbuf[0][lane] = vrow[lane];
  }
  float cge = grow[h], cbe = grow[32 + h];

  // prefetch step 1 -> regs
  float2 Rk = {0.f, 0.f}, Rq = {0.f, 0.f};
  float Rv = 0.f, Rge = 0.f, Rbe = 0.f;
  {
    size_t off = CONVD;
    Rk = *(const float2*)(krow + off + 2 * lane);
    Rq = *(const float2*)(qrow + off + 2 * lane);
    if (lane < 8) Rv = vrow[off + lane];
    Rge = grow[64 + h]; Rbe = grow[64 + 32 + h];
  }

  for (int s = 0; s < SEQ; s++) {
    const int p = s & 1;
    __syncthreads();
    // publish step s+1 into the other buffer
    if (s + 1 < SEQ) {
      ((float2*)kbuf[1 - p])[lane] = Rk;
      ((float2*)qbuf[1 - p])[lane] = Rq;
      if (lane < 8) vbuf[1 - p][lane] = Rv;
    }
    const float ge = cge, be = cbe;
    cge = Rge; cbe = Rbe;
    // issue global loads for step s+2
    if (s + 2 < SEQ) {
      size_t off = (size_t)(s + 2) * CONVD;
      Rk = *(const float2*)(krow + off + 2 * lane);
      Rq = *(const float2*)(qrow + off + 2 * lane);
      if (lane < 8) Rv = vrow[off + lane];
      Rge = grow[(s + 2) * 64 + h]; Rbe = grow[(s + 2) * 64 + 32 + h];
    }
    // read step-s fragments from LDS
    float4 k4[4], q4[4];
    #pragma unroll
    for (int m = 0; m < 4; m++) {
      k4[m] = *(const float4*)&kbuf[p][kseg * 16 + m * 4];
      q4[m] = *(const float4*)&qbuf[p][kseg * 16 + m * 4];
    }
    const float vr = vbuf[p][vs];
    const float* kr = (const float*)k4;
    const float* qr = (const float*)q4;

    // kv_mem partial over local 16 k, then intra-wave reduce over kseg
    float pp = 0.f;
    #pragma unroll
    for (int j = 0; j < 16; j++) pp += kr[j] * st[j];
    pp += __shfl_xor(pp, 8, 64);
    pp += __shfl_xor(pp, 16, 64);
    pp += __shfl_xor(pp, 32, 64);

    const float delta = be * (vr - ge * pp);

    float op = 0.f;
    #pragma unroll
    for (int j = 0; j < 16; j++) {
      st[j] = ge * st[j] + kr[j] * delta;
      op += qr[j] * st[j];
    }
    op += __shfl_xor(op, 8, 64);
    op += __shfl_xor(op, 16, 64);
    op += __shfl_xor(op, 32, 64);

    if (kseg == 0) orow[(size_t)s * VALD + vs] = op;
  }
}

// ------------- RMSNorm(1+w) * silu(z) -> bf16 -------------
__global__ __launch_bounds__(256) void rmsnorm_silu(
    const float* __restrict__ core, const float* __restrict__ zbuf,
    const float* __restrict__ norm_w, ushort* __restrict__ out_bf) {
  int t = blockIdx.x;
  int tid = threadIdx.x;
  const float* row = core + (size_t)t * VALD;
  const float* zrow = zbuf + (size_t)t * VALD;
  ushort* orow = out_bf + (size_t)t * VALD;
  float vals[16];
  float ss = 0.f;
  #pragma unroll
  for (int i = 0; i < 16; i++) { float x = row[tid + i * 256]; vals[i] = x; ss += x * x; }
  #pragma unroll
  for (int off = 32; off >= 1; off >>= 1) ss += __shfl_xor(ss, off, 64);
  __shared__ float red[4];
  if ((tid & 63) == 0) red[tid >> 6] = ss;
  __syncthreads();
  float tot = red[0] + red[1] + red[2] + red[3];
  float scale = rsqrtf(tot * (1.f / VALD) + EPSF);
  #pragma unroll
  for (int i = 0; i < 16; i++) {
    int c = tid + i * 256;
    float z = zrow[c];
    float sz = z / (1.f + expf(-z));
    orow[c] = f2bf(vals[i] * scale * (1.f + norm_w[c]) * sz);
  }
}

extern "C" void kernel_launch(void* const* d_in, const int* in_sizes, int n_in,
                              void* d_out, int out_size, void* d_ws, size_t ws_size,
                              hipStream_t stream) {
  const float* x       = (const float*)d_in[0];
  const float* W_qkvz  = (const float*)d_in[1];
  const float* W_ba    = (const float*)d_in[2];
  const float* conv_w  = (const float*)d_in[3];
  const float* dt_bias = (const float*)d_in[4];
  const float* A_log   = (const float*)d_in[5];
  const float* norm_w  = (const float*)d_in[6];
  const float* W_out   = (const float*)d_in[7];
  float* out = (float*)d_out;

  // workspace layout (floats), total 84,148,224 fl = 336.6 MB
  float* ws = (float*)d_ws;
  float* A  = ws;                         // 33,554,432 fl: qkv -> later {z | core_bf | Wz_bf}
  float* Bp = A + (size_t)33554432;       // 33,554,432 fl: Wqkv_bf -> mix -> Wo_bf
  float* Cp = Bp + (size_t)33554432;      // 16,777,216 fl: x_bf -> core
  float* ba = Cp + (size_t)16777216;      //    262,144 fl: ba -> gates (in place)

  ushort* x_bf    = (ushort*)Cp;
  ushort* Wqkv_bf = (ushort*)Bp;
  float*  zb      = A;
  ushort* core_bf = (ushort*)(A + (size_t)16777216);
  ushort* Wz_bf   = (ushort*)(A + (size_t)25165824);
  ushort* Wo_bf   = (ushort*)Bp;
  float*  mix     = Bp;
  float*  core    = Cp;

  // 1) casts for qkv projection
  cast_bf16<<<(TOK * HS / 4 + 255) / 256, 256, 0, stream>>>((const float4*)x, (ushort4*)x_bf, TOK * HS / 4);
  cast_bf16<<<(CONVD * HS / 4 + 255) / 256, 256, 0, stream>>>((const float4*)W_qkvz, (ushort4*)Wqkv_bf, CONVD * HS / 4);
  // 2) qkv projection (bf16 MFMA): [TOK, 8192]
  gemm_bf16_nt<<<dim3(CONVD / 128, TOK / 128), 256, 0, stream>>>(x_bf, Wqkv_bf, A, TOK, CONVD, HS);
  // 3) ba projection (fp32, tiny)
  gemm_nt<<<dim3(1, TOK / 64), 256, 0, stream>>>(x, W_ba, ba, TOK, 64, HS);
  // 4) conv + silu: A -> mix (frees A, overwrites Wqkv_bf in Bp)
  conv_silu<<<(int)(((size_t)TOK * CONVD) / 256), 256, 0, stream>>>(A, conv_w, mix);
  // 5) z projection: cast z-rows of W_qkvz, GEMM into A
  cast_bf16<<<(VALD * HS / 4 + 255) / 256, 256, 0, stream>>>(
      (const float4*)(W_qkvz + (size_t)(2 * KEYD + VALD) * HS), (ushort4*)Wz_bf, VALD * HS / 4);
  gemm_bf16_nt<<<dim3(VALD / 128, TOK / 128), 256, 0, stream>>>(x_bf, Wz_bf, zb, TOK, VALD, HS);
  // 6) gates (in place on ba)
  gates_kernel<<<TOK * NVH / 256, 256, 0, stream>>>(ba, A_log, dt_bias);
  // 7) l2 norm q,k (in place in mix)
  l2norm_qk<<<TOK * 32 / 4, 256, 0, stream>>>(mix);
  // 8) scan (overwrites x_bf with core — x_bf no longer needed)
  scan_kernel<<<NBATCH * NVH * 16, 64, 0, stream>>>(mix, ba, core);
  // 9) rmsnorm * silu(z) -> bf16
  rmsnorm_silu<<<TOK, 256, 0, stream>>>(core, zb, norm_w, core_bf);
  // 10) output projection: cast W_out, GEMM -> out
  cast_bf16<<<(HS * VALD / 4 + 255) / 256, 256, 0, stream>>>((const float4*)W_out, (ushort4*)Wo_bf, HS * VALD / 4);
  gemm_bf16_nt<<<dim3(HS / 128, TOK / 128), 256, 0, stream>>>(core_bf, Wo_bf, out, TOK, HS, VALD);
}

// Round 3
// 2338.008 us; speedup vs baseline: 2.7901x; 1.0172x over previous
//
#include <hip/hip_runtime.h>
#include <hip/hip_bf16.h>
#include <math.h>

#define TOK    4096   // B*S
#define HS     2048
#define CONVD  8192
#define KEYD   2048
#define VALD   4096
#define NKH    16
#define NVH    32
#define DKH    128
#define DVH    128
#define SEQ    2048
#define NBATCH 2
#define EPSF   1e-6f

typedef __attribute__((ext_vector_type(8))) short short8;
typedef __attribute__((ext_vector_type(4))) float floatx4;

static __device__ __forceinline__ unsigned short f2bf(float x) {
  union { float f; unsigned u; } c; c.f = x;
  unsigned r = (c.u + 0x7FFF + ((c.u >> 16) & 1)) >> 16;
  return (unsigned short)r;
}

// ---------------- fp32 GEMM (tiny ba projection only) ----------------
__global__ __launch_bounds__(256) void gemm_nt(
    const float* __restrict__ A, const float* __restrict__ B,
    float* __restrict__ C, int M, int N, int K) {
  __shared__ float As[16][68];
  __shared__ float Bs[16][68];
  const int tx = threadIdx.x & 15;
  const int ty = threadIdx.x >> 4;
  const int row0 = blockIdx.y * 64;
  const int col0 = blockIdx.x * 64;
  const int lr = threadIdx.x >> 2;
  const int lc = (threadIdx.x & 3) * 4;
  float acc[4][4] = {};
  for (int k0 = 0; k0 < K; k0 += 16) {
    float4 av = *(const float4*)&A[(size_t)(row0 + lr) * K + (k0 + lc)];
    float4 bv = *(const float4*)&B[(size_t)(col0 + lr) * K + (k0 + lc)];
    As[lc + 0][lr] = av.x; As[lc + 1][lr] = av.y;
    As[lc + 2][lr] = av.z; As[lc + 3][lr] = av.w;
    Bs[lc + 0][lr] = bv.x; Bs[lc + 1][lr] = bv.y;
    Bs[lc + 2][lr] = bv.z; Bs[lc + 3][lr] = bv.w;
    __syncthreads();
    #pragma unroll
    for (int kk = 0; kk < 16; kk++) {
      float a[4], b[4];
      #pragma unroll
      for (int i = 0; i < 4; i++) a[i] = As[kk][ty * 4 + i];
      #pragma unroll
      for (int i = 0; i < 4; i++) b[i] = Bs[kk][tx * 4 + i];
      #pragma unroll
      for (int i = 0; i < 4; i++)
        #pragma unroll
        for (int j = 0; j < 4; j++)
          acc[i][j] += a[i] * b[j];
    }
    __syncthreads();
  }
  #pragma unroll
  for (int i = 0; i < 4; i++) {
    float4 v = make_float4(acc[i][0], acc[i][1], acc[i][2], acc[i][3]);
    *(float4*)&C[(size_t)(row0 + ty * 4 + i) * N + (col0 + tx * 4)] = v;
  }
}

// ---------------- fp32 -> bf16 cast ----------------
__global__ __launch_bounds__(256) void cast_bf16(
    const float4* __restrict__ src, ushort4* __restrict__ dst, int n4) {
  int i = blockIdx.x * 256 + threadIdx.x;
  if (i < n4) {
    float4 v = src[i];
    ushort4 o;
    o.x = f2bf(v.x); o.y = f2bf(v.y); o.z = f2bf(v.z); o.w = f2bf(v.w);
    dst[i] = o;
  }
}

// ---------------- bf16 MFMA GEMM: C[M,N] = A[M,K] * B[N,K]^T ----------------
__global__ __launch_bounds__(256) void gemm_bf16_nt(
    const ushort* __restrict__ A, const ushort* __restrict__ B,
    float* __restrict__ C, int M, int N, int K) {
  __shared__ ushort Asm[128 * 32];
  __shared__ ushort Bsm[128 * 32];
  const int tid = threadIdx.x;
  const int w = tid >> 6, l = tid & 63;
  const int row0 = blockIdx.y * 128, col0 = blockIdx.x * 128;
  const int wm = w >> 1, wn = w & 1;

  floatx4 acc[4][4];
  #pragma unroll
  for (int i = 0; i < 4; i++)
    #pragma unroll
    for (int j = 0; j < 4; j++)
      acc[i][j] = (floatx4){0.f, 0.f, 0.f, 0.f};

  const int srow = w * 16 + (l >> 2);
  const int scol = (l & 3) * 8;
  const ushort* Ag = A + (size_t)(row0 + srow) * K + scol;
  const ushort* Bg = B + (size_t)(col0 + srow) * K + scol;

  for (int k0 = 0; k0 < K; k0 += 32) {
    #pragma unroll
    for (int c = 0; c < 2; c++) {
      __builtin_amdgcn_global_load_lds(
          (const __attribute__((address_space(1))) void*)(Ag + (size_t)(c * 64) * K + k0),
          (__attribute__((address_space(3))) void*)&Asm[(c * 64 + w * 16) * 32],
          16, 0, 0);
      __builtin_amdgcn_global_load_lds(
          (const __attribute__((address_space(1))) void*)(Bg + (size_t)(c * 64) * K + k0),
          (__attribute__((address_space(3))) void*)&Bsm[(c * 64 + w * 16) * 32],
          16, 0, 0);
    }
    __syncthreads();
    short8 af[4], bfv[4];
    #pragma unroll
    for (int i = 0; i < 4; i++) {
      af[i]  = *(const short8*)&Asm[(wm * 64 + i * 16 + (l & 15)) * 32 + (l >> 4) * 8];
      bfv[i] = *(const short8*)&Bsm[(wn * 64 + i * 16 + (l & 15)) * 32 + (l >> 4) * 8];
    }
    #pragma unroll
    for (int i = 0; i < 4; i++)
      #pragma unroll
      for (int j = 0; j < 4; j++)
        acc[i][j] = __builtin_amdgcn_mfma_f32_16x16x32_bf16(af[i], bfv[j], acc[i][j], 0, 0, 0);
    __syncthreads();
  }

  const int cl = l & 15, rq = l >> 4;
  #pragma unroll
  for (int i = 0; i < 4; i++) {
    int r0 = row0 + wm * 64 + i * 16 + rq * 4;
    #pragma unroll
    for (int j = 0; j < 4; j++) {
      int cc = col0 + wn * 64 + j * 16 + cl;
      #pragma unroll
      for (int r = 0; r < 4; r++)
        C[(size_t)(r0 + r) * N + cc] = acc[i][j][r];
    }
  }
}

// ------------- causal depthwise conv (K=4) + SiLU -------------
__global__ __launch_bounds__(256) void conv_silu(
    const float* __restrict__ qkv, const float* __restrict__ cw,
    float* __restrict__ mix) {
  size_t idx = (size_t)blockIdx.x * 256 + threadIdx.x;
  int c = (int)(idx % CONVD);
  size_t t = idx / CONVD;
  int s = (int)(t % SEQ);
  float w0 = cw[c * 4 + 0], w1 = cw[c * 4 + 1], w2 = cw[c * 4 + 2], w3 = cw[c * 4 + 3];
  const float* col = qkv + t * CONVD + c;
  float acc = w3 * col[0];
  if (s >= 1) acc += w2 * col[-(ptrdiff_t)CONVD];
  if (s >= 2) acc += w1 * col[-2 * (ptrdiff_t)CONVD];
  if (s >= 3) acc += w0 * col[-3 * (ptrdiff_t)CONVD];
  float sig = 1.f / (1.f + expf(-acc));
  mix[t * CONVD + c] = acc * sig;
}

// ------------- gates: write float2 {ge, beta} per (t, h) -------------
__global__ __launch_bounds__(256) void gates_kernel(
    const float* __restrict__ ba, const float* __restrict__ A_log,
    const float* __restrict__ dt_bias, float2* __restrict__ g2) {
  int idx = blockIdx.x * 256 + threadIdx.x;
  int h = idx & 31;
  size_t t = (size_t)(idx >> 5);
  float bv = ba[t * 64 + h];
  float av = ba[t * 64 + 32 + h];
  float beta = 1.f / (1.f + expf(-bv));
  float xx = av + dt_bias[h];
  float sp = (xx > 20.f) ? xx : log1pf(expf(xx));
  float ge = expf(-expf(A_log[h]) * sp);
  g2[t * 32 + h] = make_float2(ge, beta);
}

// ------------- per-head L2 norm of q and k (in place in mix) -------------
__global__ __launch_bounds__(256) void l2norm_qk(float* __restrict__ mix) {
  int wid = (blockIdx.x * 256 + threadIdx.x) >> 6;
  int lane = threadIdx.x & 63;
  size_t t = (size_t)(wid >> 5);
  int hh = wid & 31;
  float* p = mix + t * CONVD + (size_t)hh * DKH;
  float v0 = p[lane], v1 = p[lane + 64];
  float ss = v0 * v0 + v1 * v1;
  #pragma unroll
  for (int off = 32; off >= 1; off >>= 1) ss += __shfl_xor(ss, off, 64);
  float sc = rsqrtf(ss + EPSF);
  p[lane] = v0 * sc;
  p[lane + 64] = v1 * sc;
}

// ------------- sequential delta-rule scan: register-prefetch, no LDS -------------
// grid: 1024 = b(2) x h(32) x vc(16); 64 threads; lane = kseg(8)*8 + vs(8)
// state per lane: 16 k x 1 v. Reductions intra-wave (shfl_xor 8/16/32).
struct Frag { float4 k[4]; float4 q[4]; float v; float2 g; };

__device__ __forceinline__ void load_frag(
    Frag& f, const float* __restrict__ kp, const float* __restrict__ qp,
    const float* __restrict__ vp, const float2* __restrict__ gp, int s) {
  size_t off = (size_t)s * CONVD;
  #pragma unroll
  for (int m = 0; m < 4; m++) {
    f.k[m] = *(const float4*)(kp + off + m * 4);
    f.q[m] = *(const float4*)(qp + off + m * 4);
  }
  f.v = vp[off];
  f.g = gp[(size_t)s * 32];
}

__device__ __forceinline__ void scan_step(
    const Frag& f, float* st, float* __restrict__ orow, int s, int kseg) {
  const float* kr = (const float*)&f.k[0];
  const float* qr = (const float*)&f.q[0];
  const float ge = f.g.x, be = f.g.y;
  float a0 = 0.f, a1 = 0.f, a2 = 0.f, a3 = 0.f;
  #pragma unroll
  for (int j = 0; j < 4; j++) {
    a0 += kr[j] * st[j];
    a1 += kr[4 + j] * st[4 + j];
    a2 += kr[8 + j] * st[8 + j];
    a3 += kr[12 + j] * st[12 + j];
  }
  float pp = (a0 + a1) + (a2 + a3);
  pp += __shfl_xor(pp, 8, 64);
  pp += __shfl_xor(pp, 16, 64);
  pp += __shfl_xor(pp, 32, 64);
  const float delta = be * (f.v - ge * pp);
  float o0 = 0.f, o1 = 0.f, o2 = 0.f, o3 = 0.f;
  #pragma unroll
  for (int j = 0; j < 4; j++) {
    st[j]      = ge * st[j]      + kr[j] * delta;      o0 += qr[j] * st[j];
    st[4 + j]  = ge * st[4 + j]  + kr[4 + j] * delta;  o1 += qr[4 + j] * st[4 + j];
    st[8 + j]  = ge * st[8 + j]  + kr[8 + j] * delta;  o2 += qr[8 + j] * st[8 + j];
    st[12 + j] = ge * st[12 + j] + kr[12 + j] * delta; o3 += qr[12 + j] * st[12 + j];
  }
  float op = (o0 + o1) + (o2 + o3);
  op += __shfl_xor(op, 8, 64);
  op += __shfl_xor(op, 16, 64);
  op += __shfl_xor(op, 32, 64);
  if (kseg == 0) orow[(size_t)s * VALD] = op;
}

__global__ __launch_bounds__(64) void scan_kernel(
    const float* __restrict__ mix, const float* __restrict__ gate2,
    float* __restrict__ core) {
  const int blk = blockIdx.x;
  const int vc = blk & 15;
  const int h = (blk >> 4) & 31;
  const int b = blk >> 9;
  const int lane = threadIdx.x;
  const int kseg = lane >> 3;
  const int vs = lane & 7;
  const int kh = h >> 1;

  const float* qp = mix + (size_t)b * SEQ * CONVD + (size_t)kh * DKH + kseg * 16;
  const float* kp = qp + KEYD;
  const float* vp = mix + (size_t)b * SEQ * CONVD + 2 * KEYD + (size_t)h * DVH + vc * 8 + vs;
  const float2* gp = (const float2*)(gate2) + (size_t)b * SEQ * 32 + h;
  float* orow = core + (size_t)b * SEQ * VALD + (size_t)h * DVH + vc * 8 + vs;

  float st[16];
  #pragma unroll
  for (int i = 0; i < 16; i++) st[i] = 0.f;

  Frag F0, F1;
  load_frag(F0, kp, qp, vp, gp, 0);
  load_frag(F1, kp, qp, vp, gp, 1);

  for (int s = 0; s < SEQ; s += 2) {
    scan_step(F0, st, orow, s, kseg);
    load_frag(F0, kp, qp, vp, gp, (s + 2 < SEQ) ? s + 2 : SEQ - 1);
    scan_step(F1, st, orow, s + 1, kseg);
    load_frag(F1, kp, qp, vp, gp, (s + 3 < SEQ) ? s + 3 : SEQ - 1);
  }
}

// ------------- RMSNorm(1+w) * silu(z) -> bf16 -------------
__global__ __launch_bounds__(256) void rmsnorm_silu(
    const float* __restrict__ core, const float* __restrict__ zbuf,
    const float* __restrict__ norm_w, ushort* __restrict__ out_bf) {
  int t = blockIdx.x;
  int tid = threadIdx.x;
  const float* row = core + (size_t)t * VALD;
  const float* zrow = zbuf + (size_t)t * VALD;
  ushort* orow = out_bf + (size_t)t * VALD;
  float vals[16];
  float ss = 0.f;
  #pragma unroll
  for (int i = 0; i < 16; i++) { float x = row[tid + i * 256]; vals[i] = x; ss += x * x; }
  #pragma unroll
  for (int off = 32; off >= 1; off >>= 1) ss += __shfl_xor(ss, off, 64);
  __shared__ float red[4];
  if ((tid & 63) == 0) red[tid >> 6] = ss;
  __syncthreads();
  float tot = red[0] + red[1] + red[2] + red[3];
  float scale = rsqrtf(tot * (1.f / VALD) + EPSF);
  #pragma unroll
  for (int i = 0; i < 16; i++) {
    int c = tid + i * 256;
    float z = zrow[c];
    float sz = z / (1.f + expf(-z));
    orow[c] = f2bf(vals[i] * scale * (1.f + norm_w[c]) * sz);
  }
}

extern "C" void kernel_launch(void* const* d_in, const int* in_sizes, int n_in,
                              void* d_out, int out_size, void* d_ws, size_t ws_size,
                              hipStream_t stream) {
  const float* x       = (const float*)d_in[0];
  const float* W_qkvz  = (const float*)d_in[1];
  const float* W_ba    = (const float*)d_in[2];
  const float* conv_w  = (const float*)d_in[3];
  const float* dt_bias = (const float*)d_in[4];
  const float* A_log   = (const float*)d_in[5];
  const float* norm_w  = (const float*)d_in[6];
  const float* W_out   = (const float*)d_in[7];
  float* out = (float*)d_out;

  // workspace layout (floats), total 84,410,368 fl = 337.6 MB
  float* ws = (float*)d_ws;
  float* A  = ws;                         // 33,554,432 fl
  float* Bp = A + (size_t)33554432;       // 33,554,432 fl
  float* Cp = Bp + (size_t)33554432;      // 16,777,216 fl
  float* ba = Cp + (size_t)16777216;      //    262,144 fl
  float* g2 = ba + (size_t)262144;        //    262,144 fl (float2[TOK*32])

  ushort* x_bf    = (ushort*)Cp;
  ushort* Wqkv_bf = (ushort*)Bp;
  float*  zb      = A;
  ushort* core_bf = (ushort*)(A + (size_t)16777216);
  ushort* Wz_bf   = (ushort*)(A + (size_t)25165824);
  ushort* Wo_bf   = (ushort*)Bp;
  float*  mix     = Bp;
  float*  core    = Cp;

  // 1) casts for qkv projection
  cast_bf16<<<(TOK * HS / 4 + 255) / 256, 256, 0, stream>>>((const float4*)x, (ushort4*)x_bf, TOK * HS / 4);
  cast_bf16<<<(CONVD * HS / 4 + 255) / 256, 256, 0, stream>>>((const float4*)W_qkvz, (ushort4*)Wqkv_bf, CONVD * HS / 4);
  // 2) qkv projection (bf16 MFMA): [TOK, 8192]
  gemm_bf16_nt<<<dim3(CONVD / 128, TOK / 128), 256, 0, stream>>>(x_bf, Wqkv_bf, A, TOK, CONVD, HS);
  // 3) ba projection (fp32, tiny)
  gemm_nt<<<dim3(1, TOK / 64), 256, 0, stream>>>(x, W_ba, ba, TOK, 64, HS);
  // 4) conv + silu: A -> mix (frees A, overwrites Wqkv_bf in Bp)
  conv_silu<<<(int)(((size_t)TOK * CONVD) / 256), 256, 0, stream>>>(A, conv_w, mix);
  // 5) z projection: cast z-rows of W_qkvz, GEMM into A
  cast_bf16<<<(VALD * HS / 4 + 255) / 256, 256, 0, stream>>>(
      (const float4*)(W_qkvz + (size_t)(2 * KEYD + VALD) * HS), (ushort4*)Wz_bf, VALD * HS / 4);
  gemm_bf16_nt<<<dim3(VALD / 128, TOK / 128), 256, 0, stream>>>(x_bf, Wz_bf, zb, TOK, VALD, HS);
  // 6) gates -> float2 buffer
  gates_kernel<<<TOK * NVH / 256, 256, 0, stream>>>(ba, A_log, dt_bias, (float2*)g2);
  // 7) l2 norm q,k (in place in mix)
  l2norm_qk<<<TOK * 32 / 4, 256, 0, stream>>>(mix);
  // 8) scan (register-prefetch; overwrites x_bf region with core)
  scan_kernel<<<NBATCH * NVH * 16, 64, 0, stream>>>(mix, g2, core);
  // 9) rmsnorm * silu(z) -> bf16
  rmsnorm_silu<<<TOK, 256, 0, stream>>>(core, zb, norm_w, core_bf);
  // 10) output projection
  cast_bf16<<<(HS * VALD / 4 + 255) / 256, 256, 0, stream>>>((const float4*)W_out, (ushort4*)Wo_bf, HS * VALD / 4);
  gemm_bf16_nt<<<dim3(HS / 128, TOK / 128), 256, 0, stream>>>(core_bf, Wo_bf, out, TOK, HS, VALD);
}

// Round 4
// 2248.554 us; speedup vs baseline: 2.9010x; 1.0398x over previous
//
#include <hip/hip_runtime.h>
#include <hip/hip_bf16.h>
#include <math.h>

#define TOK    4096   // B*S
#define HS     2048
#define CONVD  8192
#define KEYD   2048
#define VALD   4096
#define NKH    16
#define NVH    32
#define DKH    128
#define DVH    128
#define SEQ    2048
#define NBATCH 2
#define EPSF   1e-6f

typedef __attribute__((ext_vector_type(8))) short short8;
typedef __attribute__((ext_vector_type(4))) float floatx4;

static __device__ __forceinline__ unsigned short f2bf(float x) {
  union { float f; unsigned u; } c; c.f = x;
  unsigned r = (c.u + 0x7FFF + ((c.u >> 16) & 1)) >> 16;
  return (unsigned short)r;
}

// ---------------- fp32 GEMM (tiny ba projection only) ----------------
__global__ __launch_bounds__(256) void gemm_nt(
    const float* __restrict__ A, const float* __restrict__ B,
    float* __restrict__ C, int M, int N, int K) {
  __shared__ float As[16][68];
  __shared__ float Bs[16][68];
  const int tx = threadIdx.x & 15;
  const int ty = threadIdx.x >> 4;
  const int row0 = blockIdx.y * 64;
  const int col0 = blockIdx.x * 64;
  const int lr = threadIdx.x >> 2;
  const int lc = (threadIdx.x & 3) * 4;
  float acc[4][4] = {};
  for (int k0 = 0; k0 < K; k0 += 16) {
    float4 av = *(const float4*)&A[(size_t)(row0 + lr) * K + (k0 + lc)];
    float4 bv = *(const float4*)&B[(size_t)(col0 + lr) * K + (k0 + lc)];
    As[lc + 0][lr] = av.x; As[lc + 1][lr] = av.y;
    As[lc + 2][lr] = av.z; As[lc + 3][lr] = av.w;
    Bs[lc + 0][lr] = bv.x; Bs[lc + 1][lr] = bv.y;
    Bs[lc + 2][lr] = bv.z; Bs[lc + 3][lr] = bv.w;
    __syncthreads();
    #pragma unroll
    for (int kk = 0; kk < 16; kk++) {
      float a[4], b[4];
      #pragma unroll
      for (int i = 0; i < 4; i++) a[i] = As[kk][ty * 4 + i];
      #pragma unroll
      for (int i = 0; i < 4; i++) b[i] = Bs[kk][tx * 4 + i];
      #pragma unroll
      for (int i = 0; i < 4; i++)
        #pragma unroll
        for (int j = 0; j < 4; j++)
          acc[i][j] += a[i] * b[j];
    }
    __syncthreads();
  }
  #pragma unroll
  for (int i = 0; i < 4; i++) {
    float4 v = make_float4(acc[i][0], acc[i][1], acc[i][2], acc[i][3]);
    *(float4*)&C[(size_t)(row0 + ty * 4 + i) * N + (col0 + tx * 4)] = v;
  }
}

// ---------------- fp32 -> bf16 cast ----------------
__global__ __launch_bounds__(256) void cast_bf16(
    const float4* __restrict__ src, ushort4* __restrict__ dst, int n4) {
  int i = blockIdx.x * 256 + threadIdx.x;
  if (i < n4) {
    float4 v = src[i];
    ushort4 o;
    o.x = f2bf(v.x); o.y = f2bf(v.y); o.z = f2bf(v.z); o.w = f2bf(v.w);
    dst[i] = o;
  }
}

// ---------------- bf16 MFMA GEMM: C[M,N] = A[M,K] * B[N,K]^T ----------------
__global__ __launch_bounds__(256) void gemm_bf16_nt(
    const ushort* __restrict__ A, const ushort* __restrict__ B,
    float* __restrict__ C, int M, int N, int K) {
  __shared__ ushort Asm[128 * 32];
  __shared__ ushort Bsm[128 * 32];
  const int tid = threadIdx.x;
  const int w = tid >> 6, l = tid & 63;
  const int row0 = blockIdx.y * 128, col0 = blockIdx.x * 128;
  const int wm = w >> 1, wn = w & 1;

  floatx4 acc[4][4];
  #pragma unroll
  for (int i = 0; i < 4; i++)
    #pragma unroll
    for (int j = 0; j < 4; j++)
      acc[i][j] = (floatx4){0.f, 0.f, 0.f, 0.f};

  const int srow = w * 16 + (l >> 2);
  const int scol = (l & 3) * 8;
  const ushort* Ag = A + (size_t)(row0 + srow) * K + scol;
  const ushort* Bg = B + (size_t)(col0 + srow) * K + scol;

  for (int k0 = 0; k0 < K; k0 += 32) {
    #pragma unroll
    for (int c = 0; c < 2; c++) {
      __builtin_amdgcn_global_load_lds(
          (const __attribute__((address_space(1))) void*)(Ag + (size_t)(c * 64) * K + k0),
          (__attribute__((address_space(3))) void*)&Asm[(c * 64 + w * 16) * 32],
          16, 0, 0);
      __builtin_amdgcn_global_load_lds(
          (const __attribute__((address_space(1))) void*)(Bg + (size_t)(c * 64) * K + k0),
          (__attribute__((address_space(3))) void*)&Bsm[(c * 64 + w * 16) * 32],
          16, 0, 0);
    }
    __syncthreads();
    short8 af[4], bfv[4];
    #pragma unroll
    for (int i = 0; i < 4; i++) {
      af[i]  = *(const short8*)&Asm[(wm * 64 + i * 16 + (l & 15)) * 32 + (l >> 4) * 8];
      bfv[i] = *(const short8*)&Bsm[(wn * 64 + i * 16 + (l & 15)) * 32 + (l >> 4) * 8];
    }
    #pragma unroll
    for (int i = 0; i < 4; i++)
      #pragma unroll
      for (int j = 0; j < 4; j++)
        acc[i][j] = __builtin_amdgcn_mfma_f32_16x16x32_bf16(af[i], bfv[j], acc[i][j], 0, 0, 0);
    __syncthreads();
  }

  const int cl = l & 15, rq = l >> 4;
  #pragma unroll
  for (int i = 0; i < 4; i++) {
    int r0 = row0 + wm * 64 + i * 16 + rq * 4;
    #pragma unroll
    for (int j = 0; j < 4; j++) {
      int cc = col0 + wn * 64 + j * 16 + cl;
      #pragma unroll
      for (int r = 0; r < 4; r++)
        C[(size_t)(r0 + r) * N + cc] = acc[i][j][r];
    }
  }
}

// ------------- causal depthwise conv (K=4) + SiLU -------------
__global__ __launch_bounds__(256) void conv_silu(
    const float* __restrict__ qkv, const float* __restrict__ cw,
    float* __restrict__ mix) {
  size_t idx = (size_t)blockIdx.x * 256 + threadIdx.x;
  int c = (int)(idx % CONVD);
  size_t t = idx / CONVD;
  int s = (int)(t % SEQ);
  float w0 = cw[c * 4 + 0], w1 = cw[c * 4 + 1], w2 = cw[c * 4 + 2], w3 = cw[c * 4 + 3];
  const float* col = qkv + t * CONVD + c;
  float acc = w3 * col[0];
  if (s >= 1) acc += w2 * col[-(ptrdiff_t)CONVD];
  if (s >= 2) acc += w1 * col[-2 * (ptrdiff_t)CONVD];
  if (s >= 3) acc += w0 * col[-3 * (ptrdiff_t)CONVD];
  float sig = 1.f / (1.f + expf(-acc));
  mix[t * CONVD + c] = acc * sig;
}

// ------------- gates: write float2 {ge, beta} per (t, h) -------------
__global__ __launch_bounds__(256) void gates_kernel(
    const float* __restrict__ ba, const float* __restrict__ A_log,
    const float* __restrict__ dt_bias, float2* __restrict__ g2) {
  int idx = blockIdx.x * 256 + threadIdx.x;
  int h = idx & 31;
  size_t t = (size_t)(idx >> 5);
  float bv = ba[t * 64 + h];
  float av = ba[t * 64 + 32 + h];
  float beta = 1.f / (1.f + expf(-bv));
  float xx = av + dt_bias[h];
  float sp = (xx > 20.f) ? xx : log1pf(expf(xx));
  float ge = expf(-expf(A_log[h]) * sp);
  g2[t * 32 + h] = make_float2(ge, beta);
}

// ------------- per-head L2 norm of q and k (in place in mix) -------------
__global__ __launch_bounds__(256) void l2norm_qk(float* __restrict__ mix) {
  int wid = (blockIdx.x * 256 + threadIdx.x) >> 6;
  int lane = threadIdx.x & 63;
  size_t t = (size_t)(wid >> 5);
  int hh = wid & 31;
  float* p = mix + t * CONVD + (size_t)hh * DKH;
  float v0 = p[lane], v1 = p[lane + 64];
  float ss = v0 * v0 + v1 * v1;
  #pragma unroll
  for (int off = 32; off >= 1; off >>= 1) ss += __shfl_xor(ss, off, 64);
  float sc = rsqrtf(ss + EPSF);
  p[lane] = v0 * sc;
  p[lane + 64] = v1 * sc;
}

// ------------- sequential delta-rule scan v3 -------------
// grid: 512 = b(2) x h(32) x vc(8); 64 threads; lane = kseg(4)*16 + vs(16)
// state per lane: 32 k x 1 v. Reductions: 2 shuffles (xor 16, 32).
// Ring-3 register prefetch pinned with sched_barrier(0).
struct Frag { float4 k[8]; float4 q[8]; float v; float2 g; };

__device__ __forceinline__ void load_frag(
    Frag& f, const float* __restrict__ kp, const float* __restrict__ qp,
    const float* __restrict__ vp, const float2* __restrict__ gp, int s) {
  size_t off = (size_t)s * CONVD;
  #pragma unroll
  for (int m = 0; m < 8; m++) {
    f.k[m] = *(const float4*)(kp + off + m * 4);
    f.q[m] = *(const float4*)(qp + off + m * 4);
  }
  f.v = vp[off];
  f.g = gp[(size_t)s * 32];
}

__device__ __forceinline__ void scan_step(
    const Frag& f, float* st, float* __restrict__ orow, int s, int kseg) {
  const float* kr = (const float*)&f.k[0];
  const float* qr = (const float*)&f.q[0];
  const float ge = f.g.x, be = f.g.y;
  float a0 = 0.f, a1 = 0.f, a2 = 0.f, a3 = 0.f;
  #pragma unroll
  for (int j = 0; j < 8; j++) {
    a0 += kr[j]      * st[j];
    a1 += kr[8 + j]  * st[8 + j];
    a2 += kr[16 + j] * st[16 + j];
    a3 += kr[24 + j] * st[24 + j];
  }
  float pp = (a0 + a1) + (a2 + a3);
  pp += __shfl_xor(pp, 16, 64);
  pp += __shfl_xor(pp, 32, 64);
  const float delta = be * (f.v - ge * pp);
  float o0 = 0.f, o1 = 0.f, o2 = 0.f, o3 = 0.f;
  #pragma unroll
  for (int j = 0; j < 8; j++) {
    st[j]      = ge * st[j]      + kr[j] * delta;      o0 += qr[j] * st[j];
    st[8 + j]  = ge * st[8 + j]  + kr[8 + j] * delta;  o1 += qr[8 + j] * st[8 + j];
    st[16 + j] = ge * st[16 + j] + kr[16 + j] * delta; o2 += qr[16 + j] * st[16 + j];
    st[24 + j] = ge * st[24 + j] + kr[24 + j] * delta; o3 += qr[24 + j] * st[24 + j];
  }
  float op = (o0 + o1) + (o2 + o3);
  op += __shfl_xor(op, 16, 64);
  op += __shfl_xor(op, 32, 64);
  if (kseg == 0) orow[(size_t)s * VALD] = op;
}

__global__ __launch_bounds__(64, 1) void scan_kernel(
    const float* __restrict__ mix, const float* __restrict__ gate2,
    float* __restrict__ core) {
  const int blk = blockIdx.x;
  const int vc = blk & 7;
  const int h = (blk >> 3) & 31;
  const int b = blk >> 8;
  const int lane = threadIdx.x;
  const int kseg = lane >> 4;
  const int vs = lane & 15;
  const int kh = h >> 1;

  const float* qp = mix + (size_t)b * SEQ * CONVD + (size_t)kh * DKH + kseg * 32;
  const float* kp = qp + KEYD;
  const float* vp = mix + (size_t)b * SEQ * CONVD + 2 * KEYD + (size_t)h * DVH + vc * 16 + vs;
  const float2* gp = (const float2*)(gate2) + (size_t)b * SEQ * 32 + h;
  float* orow = core + (size_t)b * SEQ * VALD + (size_t)h * DVH + vc * 16 + vs;

  float st[32];
  #pragma unroll
  for (int i = 0; i < 32; i++) st[i] = 0.f;

  Frag F0, F1, F2;
  load_frag(F0, kp, qp, vp, gp, 0);
  load_frag(F1, kp, qp, vp, gp, 1);
  load_frag(F2, kp, qp, vp, gp, 2);

  for (int s = 0; s < SEQ - 2; s += 3) {
    scan_step(F0, st, orow, s, kseg);
    __builtin_amdgcn_sched_barrier(0);
    load_frag(F0, kp, qp, vp, gp, s + 3);
    __builtin_amdgcn_sched_barrier(0);
    scan_step(F1, st, orow, s + 1, kseg);
    __builtin_amdgcn_sched_barrier(0);
    load_frag(F1, kp, qp, vp, gp, s + 4);
    __builtin_amdgcn_sched_barrier(0);
    scan_step(F2, st, orow, s + 2, kseg);
    __builtin_amdgcn_sched_barrier(0);
    if (s + 5 < SEQ) load_frag(F2, kp, qp, vp, gp, s + 5);
    __builtin_amdgcn_sched_barrier(0);
  }
  // steps 2046, 2047 (loaded in the final loop iteration)
  scan_step(F0, st, orow, SEQ - 2, kseg);
  scan_step(F1, st, orow, SEQ - 1, kseg);
}

// ------------- RMSNorm(1+w) * silu(z) -> bf16 -------------
__global__ __launch_bounds__(256) void rmsnorm_silu(
    const float* __restrict__ core, const float* __restrict__ zbuf,
    const float* __restrict__ norm_w, ushort* __restrict__ out_bf) {
  int t = blockIdx.x;
  int tid = threadIdx.x;
  const float* row = core + (size_t)t * VALD;
  const float* zrow = zbuf + (size_t)t * VALD;
  ushort* orow = out_bf + (size_t)t * VALD;
  float vals[16];
  float ss = 0.f;
  #pragma unroll
  for (int i = 0; i < 16; i++) { float x = row[tid + i * 256]; vals[i] = x; ss += x * x; }
  #pragma unroll
  for (int off = 32; off >= 1; off >>= 1) ss += __shfl_xor(ss, off, 64);
  __shared__ float red[4];
  if ((tid & 63) == 0) red[tid >> 6] = ss;
  __syncthreads();
  float tot = red[0] + red[1] + red[2] + red[3];
  float scale = rsqrtf(tot * (1.f / VALD) + EPSF);
  #pragma unroll
  for (int i = 0; i < 16; i++) {
    int c = tid + i * 256;
    float z = zrow[c];
    float sz = z / (1.f + expf(-z));
    orow[c] = f2bf(vals[i] * scale * (1.f + norm_w[c]) * sz);
  }
}

extern "C" void kernel_launch(void* const* d_in, const int* in_sizes, int n_in,
                              void* d_out, int out_size, void* d_ws, size_t ws_size,
                              hipStream_t stream) {
  const float* x       = (const float*)d_in[0];
  const float* W_qkvz  = (const float*)d_in[1];
  const float* W_ba    = (const float*)d_in[2];
  const float* conv_w  = (const float*)d_in[3];
  const float* dt_bias = (const float*)d_in[4];
  const float* A_log   = (const float*)d_in[5];
  const float* norm_w  = (const float*)d_in[6];
  const float* W_out   = (const float*)d_in[7];
  float* out = (float*)d_out;

  // workspace layout (floats), total 84,410,368 fl = 337.6 MB
  float* ws = (float*)d_ws;
  float* A  = ws;                         // 33,554,432 fl
  float* Bp = A + (size_t)33554432;       // 33,554,432 fl
  float* Cp = Bp + (size_t)33554432;      // 16,777,216 fl
  float* ba = Cp + (size_t)16777216;      //    262,144 fl
  float* g2 = ba + (size_t)262144;        //    262,144 fl (float2[TOK*32])

  ushort* x_bf    = (ushort*)Cp;
  ushort* Wqkv_bf = (ushort*)Bp;
  float*  zb      = A;
  ushort* core_bf = (ushort*)(A + (size_t)16777216);
  ushort* Wz_bf   = (ushort*)(A + (size_t)25165824);
  ushort* Wo_bf   = (ushort*)Bp;
  float*  mix     = Bp;
  float*  core    = Cp;

  // 1) casts for qkv projection
  cast_bf16<<<(TOK * HS / 4 + 255) / 256, 256, 0, stream>>>((const float4*)x, (ushort4*)x_bf, TOK * HS / 4);
  cast_bf16<<<(CONVD * HS / 4 + 255) / 256, 256, 0, stream>>>((const float4*)W_qkvz, (ushort4*)Wqkv_bf, CONVD * HS / 4);
  // 2) qkv projection (bf16 MFMA): [TOK, 8192]
  gemm_bf16_nt<<<dim3(CONVD / 128, TOK / 128), 256, 0, stream>>>(x_bf, Wqkv_bf, A, TOK, CONVD, HS);
  // 3) ba projection (fp32, tiny)
  gemm_nt<<<dim3(1, TOK / 64), 256, 0, stream>>>(x, W_ba, ba, TOK, 64, HS);
  // 4) conv + silu: A -> mix (frees A, overwrites Wqkv_bf in Bp)
  conv_silu<<<(int)(((size_t)TOK * CONVD) / 256), 256, 0, stream>>>(A, conv_w, mix);
  // 5) z projection: cast z-rows of W_qkvz, GEMM into A
  cast_bf16<<<(VALD * HS / 4 + 255) / 256, 256, 0, stream>>>(
      (const float4*)(W_qkvz + (size_t)(2 * KEYD + VALD) * HS), (ushort4*)Wz_bf, VALD * HS / 4);
  gemm_bf16_nt<<<dim3(VALD / 128, TOK / 128), 256, 0, stream>>>(x_bf, Wz_bf, zb, TOK, VALD, HS);
  // 6) gates -> float2 buffer
  gates_kernel<<<TOK * NVH / 256, 256, 0, stream>>>(ba, A_log, dt_bias, (float2*)g2);
  // 7) l2 norm q,k (in place in mix)
  l2norm_qk<<<TOK * 32 / 4, 256, 0, stream>>>(mix);
  // 8) scan v3 (ring-3 pinned prefetch; overwrites x_bf region with core)
  scan_kernel<<<NBATCH * NVH * 8, 64, 0, stream>>>(mix, g2, core);
  // 9) rmsnorm * silu(z) -> bf16
  rmsnorm_silu<<<TOK, 256, 0, stream>>>(core, zb, norm_w, core_bf);
  // 10) output projection
  cast_bf16<<<(HS * VALD / 4 + 255) / 256, 256, 0, stream>>>((const float4*)W_out, (ushort4*)Wo_bf, HS * VALD / 4);
  gemm_bf16_nt<<<dim3(HS / 128, TOK / 128), 256, 0, stream>>>(core_bf, Wo_bf, out, TOK, HS, VALD);
}